// Round 1
// baseline (5566.064 us; speedup 1.0000x reference)
//
#include <hip/hip_runtime.h>

// RNN with feedback projection, MI355X persistent-kernel implementation.
// B=256, T=200, D_IN=512, UNITS=1024, PROJ=512.
//
// Recurrence folded as: pre = [h | sigmoid(p) | x_t] @ [Wr; Wf; Wk] + bias  (K=2048)
//                       h   = tanh(pre)
//                       p   = h @ Wp + pb                                   (K=1024)
//
// 256 blocks = 8 batch-groups (32 rows) x 32 column-blocks. Weights are fp16,
// register-resident as MFMA B-fragments. Activations are fp16 in a fragment-
// packed double buffer in ws. Group-local barriers (32 blocks) with agent-scope
// atomics; cooperative launch guarantees co-residency.

#define T_   200
#define DIN  512
#define U_   1024
#define P_   512

typedef _Float16 f16x8 __attribute__((ext_vector_type(8)));
typedef float    f32x4 __attribute__((ext_vector_type(4)));

// ws layout (fp16 elements unless noted):
//  Wpack : [cb 32][w 4][kt 16][ct 2][lane 64][j 8] = 2,097,152 elems (4 MiB)
//  Wppack: [cb 32][w 4][kt 8][lane 64][j 8]        =   524,288 elems (1 MiB)
//  Abuf  : [g 8][buf 2][rt 2][kt 64][lane 64][j 8] = 1,048,576 elems (2 MiB)
//  bars  : [g 8][64 u32] (cnt at +0, gen at +16)   (2 KiB)
#define WPACK_ELEMS  2097152
#define WPPACK_ELEMS 524288
#define OFF_WPPACK   (4u*1024*1024)
#define OFF_ABUF     (5u*1024*1024 + 256u*1024)   // 5,505,024... see launch (computed exactly)
// exact byte offsets
#define WPACK_BYTES   4194304u
#define WPPACK_BYTES  1048576u
#define ABUF_BYTES    2097152u

__global__ __launch_bounds__(256) void prep_kernel(
    const float* __restrict__ x, const float* __restrict__ krn,
    const float* __restrict__ rk, const float* __restrict__ fk,
    const float* __restrict__ pk,
    _Float16* __restrict__ Wpack, _Float16* __restrict__ Wppack,
    _Float16* __restrict__ Abuf, unsigned* __restrict__ bars)
{
  int n = blockIdx.x * 256 + threadIdx.x;
  if (blockIdx.x == 0 && threadIdx.x < 512) bars[threadIdx.x] = 0u;

  if (n < WPACK_ELEMS) {
    // dest idx = ((((cb*4+w)*16+kt)*2+ct)*64+lane)*8+j
    int j = n & 7, lane = (n >> 3) & 63, ct = (n >> 9) & 1;
    int kt = (n >> 10) & 15, w = (n >> 14) & 3, cb = n >> 16;
    int k   = w * 512 + kt * 32 + ((lane >> 4) << 3) + j;   // combined K index
    int col = cb * 32 + ct * 16 + (lane & 15);              // UNITS column
    float v;
    if (k < 1024)       v = rk[(size_t)k * 1024 + col];           // recurrent_kernel
    else if (k < 1536)  v = fk[(size_t)(k - 1024) * 1024 + col];  // feedback_kernel
    else                v = krn[(size_t)(k - 1536) * 1024 + col]; // input kernel
    Wpack[n] = (_Float16)v;
    return;
  }
  n -= WPACK_ELEMS;
  if (n < WPPACK_ELEMS) {
    // dest idx = (((cb*4+w)*8+kt)*64+lane)*8+j
    int j = n & 7, lane = (n >> 3) & 63, kt = (n >> 9) & 7;
    int w = (n >> 12) & 3, cb = n >> 14;
    int k   = w * 256 + kt * 32 + ((lane >> 4) << 3) + j;   // h index
    int col = cb * 16 + (lane & 15);                        // PROJ column
    Wppack[n] = (_Float16)pk[(size_t)k * 512 + col];
    return;
  }
  n -= WPPACK_ELEMS;
  // Abuf buf=0 init: [g][rt][kt][lane][j], 524288 elems.
  // h region kt 0..31 -> 0 ; sigp kt 32..47 -> sigmoid(0)=0.5 ; x kt 48..63 -> x[:,0,:]
  if (n < 524288) {
    int j = n & 7, lane = (n >> 3) & 63, kt = (n >> 9) & 63;
    int rt = (n >> 15) & 1, g = n >> 16;
    float v;
    if (kt < 32)      v = 0.0f;
    else if (kt < 48) v = 0.5f;
    else {
      int dc  = (kt - 48) * 32 + ((lane >> 4) << 3) + j;
      int row = g * 32 + rt * 16 + (lane & 15);
      v = x[((size_t)row * T_ + 0) * DIN + dc];
    }
    size_t idx = (size_t)g * 131072 + (size_t)(n & 65535);  // buf=0 slot
    Abuf[idx] = (_Float16)v;
  }
}

__device__ __forceinline__ void group_barrier(unsigned* bars, int g, unsigned target)
{
  __syncthreads();   // drains this block's vmem (compiler emits vmcnt(0) before s_barrier)
  if (threadIdx.x == 0) {
    unsigned* cnt = bars + g * 64;
    unsigned* gen = bars + g * 64 + 16;
    unsigned old = __hip_atomic_fetch_add(cnt, 1u, __ATOMIC_ACQ_REL, __HIP_MEMORY_SCOPE_AGENT);
    if (old == 31u) {
      __hip_atomic_store(cnt, 0u, __ATOMIC_RELAXED, __HIP_MEMORY_SCOPE_AGENT);
      __hip_atomic_fetch_add(gen, 1u, __ATOMIC_RELEASE, __HIP_MEMORY_SCOPE_AGENT);
    } else {
      while (__hip_atomic_load(gen, __ATOMIC_RELAXED, __HIP_MEMORY_SCOPE_AGENT) < target) {
        __builtin_amdgcn_s_sleep(2);
      }
      (void)__hip_atomic_load(gen, __ATOMIC_ACQUIRE, __HIP_MEMORY_SCOPE_AGENT); // inv caches
    }
  }
  __syncthreads();
}

__global__ __launch_bounds__(256, 1) void rnn_main(
    const float* __restrict__ x, const float* __restrict__ bias,
    const float* __restrict__ pbias,
    const _Float16* __restrict__ Wpack, const _Float16* __restrict__ Wppack,
    _Float16* __restrict__ Abuf, unsigned* __restrict__ bars,
    float* __restrict__ out)
{
  const int bid = blockIdx.x;
  const int g   = bid & 7;     // batch group (rows g*32 .. g*32+31); bid%8 ~ XCD affinity
  const int cb  = bid >> 3;    // column block: UNITS cols cb*32..+32, PROJ cols cb*16..+16
  const int tid = threadIdx.x;
  const int w   = tid >> 6;    // wave id = K-quarter
  const int l   = tid & 63;

  // ---- register-resident weight fragments (fp16, MFMA B-operand layout) ----
  f16x8 wA[16][2];   // phase A: this wave's K-quarter (512) x 2 col-tiles  -> 128 VGPR
  {
    const _Float16* wb = Wpack + (((size_t)cb * 4 + w) << 14);
#pragma unroll
    for (int kt = 0; kt < 16; ++kt)
#pragma unroll
      for (int ct = 0; ct < 2; ++ct)
        wA[kt][ct] = *(const f16x8*)(wb + (((kt * 2 + ct) * 64 + l) << 3));
  }
  f16x8 wP[8];       // phase B: K-quarter (256) x 16 proj cols -> 32 VGPR
  {
    const _Float16* wb = Wppack + (((size_t)cb * 4 + w) << 12);
#pragma unroll
    for (int kt = 0; kt < 8; ++kt)
      wP[kt] = *(const f16x8*)(wb + ((kt * 64 + l) << 3));
  }

  const int rtA = w >> 1, ctA = w & 1;            // tile owned in phase-A epilogue
  const float biasv = bias[cb * 32 + ctA * 16 + (l & 15)];
  const float pbv   = pbias[cb * 16 + (l & 15)];

  __shared__ f32x4 red[4][4][64];                 // 16 KiB cross-wave K-reduction

  _Float16* abg = Abuf + (size_t)g * 131072;      // this group's double buffer
  unsigned target = 0;

  for (int t = 0; t < T_; ++t) {
    const int cur = t & 1;
    const _Float16* acur = abg + (size_t)cur * 65536;
    _Float16* anxt       = abg + (size_t)(cur ^ 1) * 65536;

    // ================= phase A: pre = A @ Wcomb ; h = tanh(pre + bias) ============
    f32x4 a00 = {0.f,0.f,0.f,0.f}, a01 = a00, a10 = a00, a11 = a00;
#pragma unroll
    for (int kt = 0; kt < 16; ++kt) {
      const int ktg = w * 16 + kt;  // this wave's K-quarter slice of kt 0..63
      f16x8 fa0 = *(const f16x8*)(acur + (size_t)ktg * 512 + l * 8);          // rows 0..15
      f16x8 fa1 = *(const f16x8*)(acur + (size_t)(64 + ktg) * 512 + l * 8);   // rows 16..31
      a00 = __builtin_amdgcn_mfma_f32_16x16x32_f16(fa0, wA[kt][0], a00, 0, 0, 0);
      a01 = __builtin_amdgcn_mfma_f32_16x16x32_f16(fa0, wA[kt][1], a01, 0, 0, 0);
      a10 = __builtin_amdgcn_mfma_f32_16x16x32_f16(fa1, wA[kt][0], a10, 0, 0, 0);
      a11 = __builtin_amdgcn_mfma_f32_16x16x32_f16(fa1, wA[kt][1], a11, 0, 0, 0);
    }
    red[w][0][l] = a00; red[w][1][l] = a01; red[w][2][l] = a10; red[w][3][l] = a11;
    __syncthreads();
    {
      // wave w owns tile w = rtA*2+ctA : sum the 4 K-partials, tanh, write h (A-frag layout)
      f32x4 s = red[0][w][l];
      s += red[1][w][l]; s += red[2][w][l]; s += red[3][w][l];
      const int gcol = cb * 32 + ctA * 16 + (l & 15);
      const int k32  = gcol & 31;           // note: h col c -> global k index c, kt' = cb
#pragma unroll
      for (int i = 0; i < 4; ++i) {
        const int grow = rtA * 16 + ((l >> 4) << 2) + i;   // C/D: row=(lane>>4)*4+reg
        float hv = tanhf(s[i] + biasv);
        const int lane2 = ((k32 >> 3) << 4) | (grow & 15);
        anxt[((size_t)rtA * 64 + cb) * 512 + lane2 * 8 + (k32 & 7)] = (_Float16)hv;
      }
    }
    group_barrier(bars, g, ++target);   // h_t globally visible within group

    // ================= phase B: p = h @ Wp + pb ; sigp = sigmoid(p) ===============
    f32x4 b0 = {0.f,0.f,0.f,0.f}, b1 = b0;
#pragma unroll
    for (int kt = 0; kt < 8; ++kt) {
      const int ktg = w * 8 + kt;   // h region kt 0..31
      f16x8 h0 = *(const f16x8*)(anxt + (size_t)ktg * 512 + l * 8);
      f16x8 h1 = *(const f16x8*)(anxt + (size_t)(64 + ktg) * 512 + l * 8);
      b0 = __builtin_amdgcn_mfma_f32_16x16x32_f16(h0, wP[kt], b0, 0, 0, 0);
      b1 = __builtin_amdgcn_mfma_f32_16x16x32_f16(h1, wP[kt], b1, 0, 0, 0);
    }
    red[w][0][l] = b0; red[w][1][l] = b1;
    __syncthreads();
    if (w < 2) {
      // wave w owns row-tile w: reduce, add pb, write p (fp32) to out, sigp (fp16) to Abuf
      f32x4 s = red[0][w][l];
      s += red[1][w][l]; s += red[2][w][l]; s += red[3][w][l];
      const int pcol = cb * 16 + (l & 15);
      const int ks   = 1024 + pcol;          // sigp global k index
      const int kt2  = ks >> 5, k32 = ks & 31;
#pragma unroll
      for (int i = 0; i < 4; ++i) {
        const int grow = w * 16 + ((l >> 4) << 2) + i;
        float pv = s[i] + pbv;
        out[(((size_t)(g * 32 + grow)) * T_ + t) * P_ + pcol] = pv;
        float sg = 1.0f / (1.0f + __expf(-pv));
        const int lane2 = ((k32 >> 3) << 4) | (grow & 15);
        anxt[((size_t)(grow >> 4) * 64 + kt2) * 512 + lane2 * 8 + (k32 & 7)] = (_Float16)sg;
      }
    } else if (w == 2 && t + 1 < T_) {
      // idle wave converts x[:, t+1, :] slice for this block into next A-buffer
      const int r = l >> 1, oct = l & 1;
      const int dc0 = cb * 16 + oct * 8;
      const float* xp = x + (((size_t)(g * 32 + r)) * T_ + (t + 1)) * DIN + dc0;
      f16x8 v;
#pragma unroll
      for (int j = 0; j < 8; ++j) v[j] = (_Float16)xp[j];
      const int k = 1536 + dc0;
      const int kt2 = k >> 5, k32 = k & 31;
      const int lane2 = ((k32 >> 3) << 4) | (r & 15);
      *(f16x8*)(anxt + ((size_t)(r >> 4) * 64 + kt2) * 512 + lane2 * 8) = v;
    }
    group_barrier(bars, g, ++target);   // sigp_t + x_{t+1} visible; next step may proceed
  }
}

extern "C" void kernel_launch(void* const* d_in, const int* in_sizes, int n_in,
                              void* d_out, int out_size, void* d_ws, size_t ws_size,
                              hipStream_t stream)
{
  const float* x    = (const float*)d_in[0];
  const float* krn  = (const float*)d_in[1];
  const float* rk   = (const float*)d_in[2];
  const float* fk   = (const float*)d_in[3];
  const float* pk   = (const float*)d_in[4];
  const float* bias = (const float*)d_in[5];
  const float* pb   = (const float*)d_in[6];
  float* out = (float*)d_out;

  char* ws = (char*)d_ws;
  _Float16* Wpack  = (_Float16*)(ws);
  _Float16* Wppack = (_Float16*)(ws + WPACK_BYTES);
  _Float16* Abuf   = (_Float16*)(ws + WPACK_BYTES + WPPACK_BYTES);
  unsigned* bars   = (unsigned*)(ws + WPACK_BYTES + WPPACK_BYTES + ABUF_BYTES);
  // total ws use: 4 MiB + 1 MiB + 2 MiB + 2 KiB ~= 7.0 MiB

  // pack weights (fp16 B-fragments), init A-buffer t=0, zero barriers
  hipLaunchKernelGGL(prep_kernel, dim3(12288), dim3(256), 0, stream,
                     x, krn, rk, fk, pk, Wpack, Wppack, Abuf, bars);

  // persistent cooperative kernel: 256 blocks (1/CU), 256 threads
  void* args[] = { (void*)&x, (void*)&bias, (void*)&pb, (void*)&Wpack, (void*)&Wppack,
                   (void*)&Abuf, (void*)&bars, (void*)&out };
  hipLaunchCooperativeKernel((void*)rnn_main, dim3(256), dim3(256), args, 0, stream);
}

// Round 2
// 3339.381 us; speedup vs baseline: 1.6668x; 1.6668x over previous
//
#include <hip/hip_runtime.h>

// RNN with feedback projection, MI355X persistent-kernel implementation, R2.
// B=256, T=200, D_IN=512, UNITS=1024, PROJ=512.
//
// pre = [h | sigmoid(p) | x_t] @ [Wr; Wf; Wk] + bias  (K=2048)
// h   = tanh(pre) ;  p = h @ Wp + pb                  (K=1024)
//
// 256 blocks = 8 batch-groups (32 rows) x 32 column-blocks, cooperative launch.
// KEY CHANGE vs R1: zero cache-maintenance coherence. All inter-block data
// moves via RELAXED agent-scope 8B atomics (sc-flagged, LLC-coherent, no
// buffer_wbl2/buffer_inv). Barrier is relaxed atomics + explicit s_waitcnt.
// x is read as fp32 directly by wave 3 (read-only -> ordinary cached loads).

#define T_   200
#define DIN  512
#define U_   1024
#define P_   512

typedef _Float16 f16x8 __attribute__((ext_vector_type(8)));
typedef float    f32x4 __attribute__((ext_vector_type(4)));
typedef unsigned long long u64;

#define WPACK_ELEMS    2097152
#define WPPACK_ELEMS   524288
#define ABUFINIT_ELEMS 393216
#define WPACK_BYTES    4194304u
#define WPPACK_BYTES   1048576u
#define ABUF_BYTES     1572864u
#define AB_GROUP       98304      // f16 elems per group (2 bufs)
#define AB_BUF         49152      // f16 elems per buffer: [rt 2][kt 48][lane 64][j 8]

#define MFMA16(a, b, c) __builtin_amdgcn_mfma_f32_16x16x32_f16((a), (b), (c), 0, 0, 0)

__global__ __launch_bounds__(256) void prep_kernel(
    const float* __restrict__ krn, const float* __restrict__ rk,
    const float* __restrict__ fk, const float* __restrict__ pk,
    _Float16* __restrict__ Wpack, _Float16* __restrict__ Wppack,
    _Float16* __restrict__ Abuf, unsigned* __restrict__ bars)
{
  int n = blockIdx.x * 256 + threadIdx.x;
  if (blockIdx.x == 0 && threadIdx.x < 512) bars[threadIdx.x] = 0u;

  if (n < WPACK_ELEMS) {
    // [cb 32][w 4][kt 16][ct 2][lane 64][j 8]; k = w*512+kt*32+((lane>>4)<<3)+j
    int j = n & 7, lane = (n >> 3) & 63, ct = (n >> 9) & 1;
    int kt = (n >> 10) & 15, w = (n >> 14) & 3, cb = n >> 16;
    int k   = w * 512 + kt * 32 + ((lane >> 4) << 3) + j;
    int col = cb * 32 + ct * 16 + (lane & 15);
    float v;
    if (k < 1024)       v = rk[(size_t)k * 1024 + col];
    else if (k < 1536)  v = fk[(size_t)(k - 1024) * 1024 + col];
    else                v = krn[(size_t)(k - 1536) * 1024 + col];
    Wpack[n] = (_Float16)v;
    return;
  }
  n -= WPACK_ELEMS;
  if (n < WPPACK_ELEMS) {
    // [cb 32][w 4][kt 8][lane 64][j 8]; k = w*256+kt*32+((lane>>4)<<3)+j
    int j = n & 7, lane = (n >> 3) & 63, kt = (n >> 9) & 7;
    int w = (n >> 12) & 3, cb = n >> 14;
    int k   = w * 256 + kt * 32 + ((lane >> 4) << 3) + j;
    int col = cb * 16 + (lane & 15);
    Wppack[n] = (_Float16)pk[(size_t)k * 512 + col];
    return;
  }
  n -= WPPACK_ELEMS;
  if (n < ABUFINIT_ELEMS) {
    // buf0 init per group: kt<32 (h) -> 0 ; kt 32..47 (sigp) -> sigmoid(0)=0.5
    int g = n / AB_BUF;
    int q = n % AB_BUF;
    int kt = (q >> 9) % 48;
    Abuf[(size_t)g * AB_GROUP + q] = (_Float16)((kt < 32) ? 0.0f : 0.5f);
  }
}

// ---- LLC-coherent (agent-scope, relaxed, no cache maintenance) primitives ----
__device__ __forceinline__ f16x8 llc_load8(const _Float16* p) {
  u64 lo = __hip_atomic_load((const u64*)p,     __ATOMIC_RELAXED, __HIP_MEMORY_SCOPE_AGENT);
  u64 hi = __hip_atomic_load((const u64*)p + 1, __ATOMIC_RELAXED, __HIP_MEMORY_SCOPE_AGENT);
  union { u64 u[2]; f16x8 v; } c; c.u[0] = lo; c.u[1] = hi; return c.v;
}
__device__ __forceinline__ void llc_store4(_Float16* p, const _Float16* src) {
  u64 q; __builtin_memcpy(&q, src, 8);
  __hip_atomic_store((u64*)p, q, __ATOMIC_RELAXED, __HIP_MEMORY_SCOPE_AGENT);
}

// Group barrier: no wbl2/inv. Release = drain own vmcnt before signaling
// (write-through stores are globally visible once vmcnt retires them).
// Acquire = poll (loads after the branch cannot issue early; sc-flagged data
// loads bypass L1/L2 so no stale cache lines are involved).
__device__ __forceinline__ void group_barrier(unsigned* bars, int g, unsigned target)
{
  asm volatile("" ::: "memory");
  __builtin_amdgcn_s_waitcnt(0);          // all prior LLC stores drained
  __syncthreads();
  if (threadIdx.x == 0) {
    unsigned* cnt = bars + g * 64;
    unsigned* gen = bars + g * 64 + 16;
    unsigned old = __hip_atomic_fetch_add(cnt, 1u, __ATOMIC_RELAXED, __HIP_MEMORY_SCOPE_AGENT);
    if (old == 31u) {
      __hip_atomic_store(cnt, 0u, __ATOMIC_RELAXED, __HIP_MEMORY_SCOPE_AGENT);
      __builtin_amdgcn_s_waitcnt(0);      // cnt reset visible before gen bump
      __hip_atomic_fetch_add(gen, 1u, __ATOMIC_RELAXED, __HIP_MEMORY_SCOPE_AGENT);
    } else {
      while (__hip_atomic_load(gen, __ATOMIC_RELAXED, __HIP_MEMORY_SCOPE_AGENT) < target) {
        __builtin_amdgcn_s_sleep(1);
      }
    }
  }
  asm volatile("" ::: "memory");
  __syncthreads();
}

__global__ __launch_bounds__(256, 1) void rnn_main(
    const float* __restrict__ x, const float* __restrict__ bias,
    const float* __restrict__ pbias,
    const _Float16* __restrict__ Wpack, const _Float16* __restrict__ Wppack,
    _Float16* __restrict__ Abuf, unsigned* __restrict__ bars,
    float* __restrict__ out)
{
  const int bid = blockIdx.x;
  const int g   = bid & 7;     // batch group (32 rows); bid%8 ~ XCD affinity heuristic
  const int cb  = bid >> 3;    // UNITS cols cb*32..+32, PROJ cols cb*16..+16
  const int tid = threadIdx.x;
  const int w   = tid >> 6;    // wave id = K-quarter
  const int l   = tid & 63;

  // register/AGPR-resident weight fragments (fp16, MFMA B-operand layout)
  f16x8 wA[16][2];
  {
    const _Float16* wb = Wpack + (((size_t)cb * 4 + w) << 14);
#pragma unroll
    for (int kt = 0; kt < 16; ++kt)
#pragma unroll
      for (int ct = 0; ct < 2; ++ct)
        wA[kt][ct] = *(const f16x8*)(wb + (((kt * 2 + ct) * 64 + l) << 3));
  }
  f16x8 wP[8];
  {
    const _Float16* wb = Wppack + (((size_t)cb * 4 + w) << 12);
#pragma unroll
    for (int kt = 0; kt < 8; ++kt)
      wP[kt] = *(const f16x8*)(wb + ((kt * 64 + l) << 3));
  }

  const int rtA = w >> 1, ctA = w & 1;
  const float biasv = bias[cb * 32 + ctA * 16 + (l & 15)];
  const float pbv   = pbias[cb * 16 + (l & 15)];

  __shared__ f32x4 red[4][4][64];      // 16 KiB cross-wave K-reduction
  __shared__ _Float16 hs[32][40];      // h tile transpose staging (+8 pad)
  __shared__ _Float16 ps[32][24];      // sigp tile transpose staging

  _Float16* abg = Abuf + (size_t)g * AB_GROUP;
  unsigned target = 0;

  // wave-3 x addressing: row = g*32 + rt*16 + (l&15), octet base col = (l>>4)*8
  const float* xrow0 = x + (size_t)(g * 32 + (l & 15)) * T_ * DIN;
  const float* xrow1 = x + (size_t)(g * 32 + 16 + (l & 15)) * T_ * DIN;
  const int xco = (l >> 4) << 3;

  for (int t = 0; t < T_; ++t) {
    const _Float16* acur = abg + (size_t)(t & 1) * AB_BUF;
    _Float16* anxt       = abg + (size_t)((t & 1) ^ 1) * AB_BUF;

    // ============ phase A: pre = [h|sigp|x] @ Wcomb ; h = tanh(pre+bias) ============
    f32x4 a00 = {0.f,0.f,0.f,0.f}, a01 = a00, a10 = a00, a11 = a00;
    if (w < 3) {
      // waves 0,1: h (K 0..1023); wave 2: sigp (K 1024..1535) — LLC loads
#pragma unroll
      for (int kt = 0; kt < 16; ++kt) {
        const int ktg = w * 16 + kt;
        f16x8 fa0 = llc_load8(acur + (size_t)ktg * 512 + l * 8);
        f16x8 fa1 = llc_load8(acur + (size_t)(48 + ktg) * 512 + l * 8);
        a00 = MFMA16(fa0, wA[kt][0], a00);
        a01 = MFMA16(fa0, wA[kt][1], a01);
        a10 = MFMA16(fa1, wA[kt][0], a10);
        a11 = MFMA16(fa1, wA[kt][1], a11);
      }
    } else {
      // wave 3: x (K 1536..2047) — ordinary cached fp32 loads + cvt
      const float* xp0 = xrow0 + (size_t)t * DIN + xco;
      const float* xp1 = xrow1 + (size_t)t * DIN + xco;
#pragma unroll
      for (int kt = 0; kt < 16; ++kt) {
        float4 u0 = *(const float4*)(xp0 + kt * 32);
        float4 u1 = *(const float4*)(xp0 + kt * 32 + 4);
        float4 v0 = *(const float4*)(xp1 + kt * 32);
        float4 v1 = *(const float4*)(xp1 + kt * 32 + 4);
        f16x8 fa0, fa1;
        fa0[0]=(_Float16)u0.x; fa0[1]=(_Float16)u0.y; fa0[2]=(_Float16)u0.z; fa0[3]=(_Float16)u0.w;
        fa0[4]=(_Float16)u1.x; fa0[5]=(_Float16)u1.y; fa0[6]=(_Float16)u1.z; fa0[7]=(_Float16)u1.w;
        fa1[0]=(_Float16)v0.x; fa1[1]=(_Float16)v0.y; fa1[2]=(_Float16)v0.z; fa1[3]=(_Float16)v0.w;
        fa1[4]=(_Float16)v1.x; fa1[5]=(_Float16)v1.y; fa1[6]=(_Float16)v1.z; fa1[7]=(_Float16)v1.w;
        a00 = MFMA16(fa0, wA[kt][0], a00);
        a01 = MFMA16(fa0, wA[kt][1], a01);
        a10 = MFMA16(fa1, wA[kt][0], a10);
        a11 = MFMA16(fa1, wA[kt][1], a11);
      }
    }
    red[w][0][l] = a00; red[w][1][l] = a01; red[w][2][l] = a10; red[w][3][l] = a11;
    __syncthreads();
    {
      // wave w owns tile (rtA, ctA): reduce K-partials, tanh, stage in LDS
      f32x4 s = red[0][w][l];
      s += red[1][w][l]; s += red[2][w][l]; s += red[3][w][l];
      const int c = ctA * 16 + (l & 15);
#pragma unroll
      for (int i = 0; i < 4; ++i) {
        const int r = rtA * 16 + ((l >> 4) << 2) + i;
        hs[r][c] = (_Float16)tanhf(s[i] + biasv);
      }
    }
    __syncthreads();
    // h -> LLC in A-frag layout, 8B packed stores. 128 units: [rt 2][row16 16][octet 4]
    if (tid < 128) {
      const int rt = tid >> 6, u = tid & 63;
      const int row16 = u & 15, o = u >> 4;
      _Float16 tmp[8];
#pragma unroll
      for (int jj = 0; jj < 8; ++jj) tmp[jj] = hs[rt * 16 + row16][o * 8 + jj];
      _Float16* dst = anxt + ((size_t)(rt * 48 + cb) * 512 + ((o << 4) | row16) * 8);
      llc_store4(dst, tmp);
      llc_store4(dst + 4, tmp + 4);
    }
    group_barrier(bars, g, ++target);   // h_t visible group-wide

    // ================= phase B: p = h @ Wp + pb ; sigp = sigmoid(p) =================
    f32x4 b0 = {0.f,0.f,0.f,0.f}, b1 = b0;
#pragma unroll
    for (int kt = 0; kt < 8; ++kt) {
      const int ktg = w * 8 + kt;
      f16x8 h0 = llc_load8(anxt + (size_t)ktg * 512 + l * 8);
      f16x8 h1 = llc_load8(anxt + (size_t)(48 + ktg) * 512 + l * 8);
      b0 = MFMA16(h0, wP[kt], b0);
      b1 = MFMA16(h1, wP[kt], b1);
    }
    red[w][0][l] = b0; red[w][1][l] = b1;
    __syncthreads();
    if (w < 2) {
      // wave w owns row-tile w: reduce, +pb, fp32 out store, sigmoid -> LDS
      f32x4 s = red[0][w][l];
      s += red[1][w][l]; s += red[2][w][l]; s += red[3][w][l];
      const int pcol = cb * 16 + (l & 15);
#pragma unroll
      for (int i = 0; i < 4; ++i) {
        const int grow = w * 16 + ((l >> 4) << 2) + i;
        float pv = s[i] + pbv;
        out[((size_t)(g * 32 + grow) * T_ + t) * P_ + pcol] = pv;
        ps[grow][l & 15] = (_Float16)(1.0f / (1.0f + __expf(-pv)));
      }
    }
    __syncthreads();
    // sigp -> LLC, 8B packed. 64 units: [rt 2][row16 16][octet 2]
    if (tid < 64) {
      const int rt = tid >> 5, u2 = tid & 31;
      const int row16 = u2 & 15, o = u2 >> 4;
      const int kt2 = 32 + (cb >> 1);
      const int oo  = ((cb & 1) << 1) | o;
      _Float16 tmp[8];
#pragma unroll
      for (int jj = 0; jj < 8; ++jj) tmp[jj] = ps[rt * 16 + row16][o * 8 + jj];
      _Float16* dst = anxt + ((size_t)(rt * 48 + kt2) * 512 + ((oo << 4) | row16) * 8);
      llc_store4(dst, tmp);
      llc_store4(dst + 4, tmp + 4);
    }
    group_barrier(bars, g, ++target);   // sigp_t visible; next step may proceed
  }
}

extern "C" void kernel_launch(void* const* d_in, const int* in_sizes, int n_in,
                              void* d_out, int out_size, void* d_ws, size_t ws_size,
                              hipStream_t stream)
{
  const float* x    = (const float*)d_in[0];
  const float* krn  = (const float*)d_in[1];
  const float* rk   = (const float*)d_in[2];
  const float* fk   = (const float*)d_in[3];
  const float* pk   = (const float*)d_in[4];
  const float* bias = (const float*)d_in[5];
  const float* pb   = (const float*)d_in[6];
  float* out = (float*)d_out;

  char* ws = (char*)d_ws;
  _Float16* Wpack  = (_Float16*)(ws);
  _Float16* Wppack = (_Float16*)(ws + WPACK_BYTES);
  _Float16* Abuf   = (_Float16*)(ws + WPACK_BYTES + WPPACK_BYTES);
  unsigned* bars   = (unsigned*)(ws + WPACK_BYTES + WPPACK_BYTES + ABUF_BYTES);
  // ws use: 4 MiB + 1 MiB + 1.5 MiB + 2 KiB

  // pack weights, init step-0 activation buffer, zero barriers (every launch:
  // harness re-poisons ws to 0xAA before each timed call)
  hipLaunchKernelGGL(prep_kernel, dim3(11776), dim3(256), 0, stream,
                     krn, rk, fk, pk, Wpack, Wppack, Abuf, bars);

  void* args[] = { (void*)&x, (void*)&bias, (void*)&pb, (void*)&Wpack, (void*)&Wppack,
                   (void*)&Abuf, (void*)&bars, (void*)&out };
  hipLaunchCooperativeKernel((void*)rnn_main, dim3(256), dim3(256), args, 0, stream);
}